// Round 5
// baseline (352.880 us; speedup 1.0000x reference)
//
#include <hip/hip_runtime.h>
#include <hip/hip_cooperative_groups.h>

namespace cg = cooperative_groups;

// HMM count-accumulation, single cooperative kernel.
// out = [trans_count 65*65=4225 | emit_count 500000*64=32M] floats.
//
// R1/R2: scattered device-scope atomics plateau at ~165us (occupancy-blind).
// R3/R4: bucket-by-partition works; total now dominated by harness fixed cost
// (512MB poison ~78us + 160MB d_in restore ~50us). R5: fuse all phases into
// one cooperative kernel (visible in top-5 for attribution), single token
// read, LDS-cached keys, u16-packed per-partition counts, float4 emit sweep.

constexpr int N_WORDS  = 500000;
constexpr int N_LABELS = 64;
constexpr int SEQ_LEN  = 512;
constexpr int BINS     = (N_LABELS + 1) * (N_LABELS + 1);   // 4225
constexpr int P        = 1000;     // emit partitions; P*CPP == 32,000,000 exactly
constexpr int CPP      = 32000;    // cells/partition; u16 counts = 64,000 B LDS
constexpr int CAP      = 8192;     // key slots/partition (mean ~3150, huge margin)
constexpr int B        = 1024;     // threads/block
constexpr int MAXG     = 512;      // 2 blocks/CU x 256 CU (LDS-limited)
constexpr int TILE_TOK = 8192;     // tokens per phase-A tile
constexpr int QPT      = TILE_TOK / 4;              // 2048 quads/tile
constexpr size_t DYN_BYTES = (size_t)(CPP / 2) * 4; // 64,000 B dynamic LDS

// dyn overlay, phase A: keybuf u32[8192] | trans u32[4225] | cnt/base/pos u32[1024]x3
//                        = 15489 u32 <= 16000
// dyn overlay, phase B: hist u32[16000] (u16-packed counts for one partition)

__global__ __launch_bounds__(B)
void fused(const int* __restrict__ words, const int* __restrict__ labels,
           unsigned* __restrict__ cursors,       // [P]
           unsigned short* __restrict__ keys,    // [P][CAP]
           unsigned* __restrict__ part_t,        // [G][BINS]
           float* __restrict__ out, int n) {
    extern __shared__ unsigned dyn[];
    cg::grid_group grid = cg::this_grid();
    const int tid = threadIdx.x, bid = blockIdx.x, G = gridDim.x;

    // ---- zero reservation cursors (replaces host memset) ----
    for (int c = bid * B + tid; c < P; c += G * B) cursors[c] = 0u;
    grid.sync();

    unsigned* keybuf = dyn;                  // [8192] packed (p<<16)|loc, ~0u = pad
    unsigned* trans  = dyn + 8192;           // [4225]
    unsigned* cnt    = dyn + 8192 + BINS;    // [1024]
    unsigned* base_  = cnt + 1024;
    unsigned* pos    = base_ + 1024;

    for (int k = tid; k < BINS; k += B) trans[k] = 0u;

    const int nquads = n >> 2;
    const int ntiles = (nquads + QPT - 1) / QPT;

    for (int tile = bid; tile < ntiles; tile += G) {
        const int q0 = tile * QPT;
        const int tq = min(QPT, nquads - q0);
        for (int k = tid; k < P; k += B) { cnt[k] = 0u; pos[k] = 0u; }
        __syncthreads();

        // pass A: single global read; keys -> LDS; partition counts; trans hist
        for (int lq = tid; lq < tq; lq += B) {
            const int q = q0 + lq;
            const int i = q << 2;
            const int4 w4 = reinterpret_cast<const int4*>(words)[q];
            const int4 l4 = reinterpret_cast<const int4*>(labels)[q];
            const int j0 = i & (SEQ_LEN - 1);
            int pre = (j0 == 0) ? N_LABELS : labels[i - 1];
            int wv[4] = {w4.x, w4.y, w4.z, w4.w};
            int lv[4] = {l4.x, l4.y, l4.z, l4.w};
            unsigned pk[4];
            #pragma unroll
            for (int k = 0; k < 4; ++k) {
                const int lab = lv[k];
                unsigned pack = 0xFFFFFFFFu;
                if (wv[k] != 0) {
                    atomicAdd(&trans[lab * (N_LABELS + 1) + pre], 1u);
                    const int w = (wv[k] >= N_WORDS) ? 1 : wv[k];
                    const unsigned key = (unsigned)w * N_LABELS + (unsigned)lab;
                    const unsigned p   = key / CPP;      // const-div -> magic mul
                    pack = (p << 16) | (key - p * CPP);
                    atomicAdd(&cnt[p], 1u);
                }
                pk[k] = pack;
                pre = lab;
            }
            reinterpret_cast<uint4*>(keybuf)[lq] =
                make_uint4(pk[0], pk[1], pk[2], pk[3]);   // b128, conflict-free
        }
        __syncthreads();

        // reservation: ONE device atomic per (block, partition)
        for (int p = tid; p < P; p += B) {
            const unsigned c = cnt[p];
            base_[p] = c ? atomicAdd(&cursors[p], c) : 0u;
        }
        __syncthreads();

        // pass B: place keys from LDS (no global re-read)
        const int tt = tq << 2;
        for (int t = tid; t < tt; t += B) {
            const unsigned pack = keybuf[t];
            if (pack != 0xFFFFFFFFu) {
                const unsigned p    = pack >> 16;
                const unsigned loc  = pack & 0xFFFFu;
                const unsigned slot = base_[p] + atomicAdd(&pos[p], 1u);
                if (slot < CAP)
                    keys[(size_t)p * CAP + slot] = (unsigned short)loc;
            }
        }
        __syncthreads();
    }

    // flush trans partial (plain coalesced stores)
    {
        unsigned* my = part_t + (size_t)bid * BINS;
        for (int k = tid; k < BINS; k += B) my[k] = trans[k];
    }
    grid.sync();

    // ---- phase B: build emit slices (writes ALL 32M cells -> no zero pass) ----
    float* __restrict__ emit = out + BINS;
    for (int p = bid; p < P; p += G) {
        for (int j = tid; j < CPP / 2; j += B) dyn[j] = 0u;
        __syncthreads();
        unsigned nk = cursors[p]; if (nk > CAP) nk = CAP;
        const unsigned short* kp = keys + (size_t)p * CAP;
        for (unsigned i = tid; i < nk; i += B)
            atomicAdd(&dyn[kp[i] >> 1], (kp[i] & 1u) ? 65536u : 1u);
        __syncthreads();
        // write sweep; emit+p*CPP is ==4 (mod 16) aligned -> 3-cell prologue,
        // float4 over cells 3..31998, 1-cell epilogue
        float* dst = emit + (size_t)p * CPP;
        if (tid < 3)
            dst[tid] = (float)((dyn[tid >> 1] >> ((tid & 1u) * 16)) & 0xFFFFu);
        if (tid == 3)
            dst[CPP - 1] = (float)(dyn[(CPP - 1) >> 1] >> 16);
        float4* dst4 = reinterpret_cast<float4*>(dst + 3);
        for (int u = tid; u < (CPP - 4) / 4; u += B) {      // 7999 float4s
            const unsigned w0 = dyn[2 * u + 1];
            const unsigned w1 = dyn[2 * u + 2];
            const unsigned w2 = dyn[2 * u + 3];
            float4 f;
            f.x = (float)(w0 >> 16);
            f.y = (float)(w1 & 0xFFFFu);
            f.z = (float)(w1 >> 16);
            f.w = (float)(w2 & 0xFFFFu);
            dst4[u] = f;
        }
        __syncthreads();
    }

    // fused trans finalize (blocks 0..4 after their partitions)
    for (int k = bid * B + tid; k < BINS; k += G * B) {
        unsigned s = 0;
        for (int pb = 0; pb < G; ++pb) s += part_t[(size_t)pb * BINS + k];
        out[k] = (float)s;
    }
}

// ---------------- fallback (ws too small / coop launch refused) ----------------

__global__ __launch_bounds__(256)
void zero_kernel(uint4* __restrict__ out, int out_quads, int out_size) {
    const uint4 z = {0u, 0u, 0u, 0u};
    const int stride = gridDim.x * blockDim.x;
    for (int q = blockIdx.x * blockDim.x + threadIdx.x; q < out_quads; q += stride)
        out[q] = z;
    if (blockIdx.x == 0 && threadIdx.x < (out_size & 3))
        ((unsigned*)out)[(out_quads << 2) + threadIdx.x] = 0u;
}

__global__ __launch_bounds__(1024)
void count_fallback(const int* __restrict__ words, const int* __restrict__ labels,
                    float* __restrict__ out, int nquads) {
    __shared__ unsigned hist[BINS];
    for (int k = threadIdx.x; k < BINS; k += 1024) hist[k] = 0u;
    __syncthreads();
    float* __restrict__ emit = out + BINS;
    const int stride = gridDim.x * blockDim.x;
    for (int q = blockIdx.x * blockDim.x + threadIdx.x; q < nquads; q += stride) {
        const int i = q << 2;
        const int4 w4 = reinterpret_cast<const int4*>(words)[q];
        const int4 l4 = reinterpret_cast<const int4*>(labels)[q];
        const int j0 = i & (SEQ_LEN - 1);
        int pre = (j0 == 0) ? N_LABELS : labels[i - 1];
        int wv[4] = {w4.x, w4.y, w4.z, w4.w};
        int lv[4] = {l4.x, l4.y, l4.z, l4.w};
        #pragma unroll
        for (int k = 0; k < 4; ++k) {
            const int w = wv[k], lab = lv[k];
            if (w != 0) {
                atomicAdd(&hist[lab * (N_LABELS + 1) + pre], 1u);
                const int we = (w >= N_WORDS) ? 1 : w;
                atomicAdd(&emit[(size_t)we * N_LABELS + lab], 1.0f);
            }
            pre = lab;
        }
    }
    __syncthreads();
    for (int k = threadIdx.x; k < BINS; k += 1024) {
        const unsigned c = hist[k];
        if (c) atomicAdd(&out[k], (float)c);
    }
}

// ---------------- launch ----------------

extern "C" void kernel_launch(void* const* d_in, const int* in_sizes, int n_in,
                              void* d_out, int out_size, void* d_ws, size_t ws_size,
                              hipStream_t stream) {
    const int* words  = (const int*)d_in[0];
    const int* labels = (const int*)d_in[1];
    float* out = (float*)d_out;
    const int n = in_sizes[0];

    // ws: cursors 4KB | keys P*CAP*2 = 16.4MB | part_t MAXG*BINS*4 = 8.65MB
    const size_t key_off    = 4096;
    const size_t key_bytes  = (size_t)P * CAP * sizeof(unsigned short);
    const size_t part_off   = key_off + key_bytes;
    const size_t part_bytes = (size_t)MAXG * BINS * sizeof(unsigned);
    const size_t need       = part_off + part_bytes;

    // One-time grid sizing (first call is the correctness call, pre-capture).
    static int G = 0;
    if (G == 0) {
        int nb = 0;
        if (hipOccupancyMaxActiveBlocksPerMultiprocessor(
                &nb, (const void*)fused, B, DYN_BYTES) != hipSuccess || nb < 1)
            nb = 1;
        int dev = 0; hipGetDevice(&dev);
        hipDeviceProp_t prop;
        int cus = (hipGetDeviceProperties(&prop, dev) == hipSuccess)
                      ? prop.multiProcessorCount : 256;
        int g = nb * cus;
        G = g < 1 ? 1 : (g > MAXG ? MAXG : g);
    }

    bool ok = false;
    if (ws_size >= need) {
        unsigned* cursors    = (unsigned*)d_ws;
        unsigned short* keys = (unsigned short*)((char*)d_ws + key_off);
        unsigned* part_t     = (unsigned*)((char*)d_ws + part_off);
        void* args[] = {(void*)&words, (void*)&labels, (void*)&cursors,
                        (void*)&keys, (void*)&part_t, (void*)&out, (void*)&n};
        ok = (hipLaunchCooperativeKernel((const void*)fused, dim3(G), dim3(B),
                                         args, DYN_BYTES, stream) == hipSuccess);
    }
    if (!ok) {
        const int out_quads = out_size >> 2;
        zero_kernel<<<2048, 256, 0, stream>>>((uint4*)d_out, out_quads, out_size);
        count_fallback<<<512, 1024, 0, stream>>>(words, labels, out, n >> 2);
    }
}

// Round 6
// 266.516 us; speedup vs baseline: 1.3240x; 1.3240x over previous
//
#include <hip/hip_runtime.h>
#include <hip/hip_bf16.h>

// HMM count-accumulation with NO scattered global writes.
// out = [trans_count 65*65=4225 | emit_count 500000*64=32M] floats.
//
// Measured walls: scattered device-scope atomics (R1: 3.15M -> 165us) AND
// scattered u16 stores (R5: fused kernel 234us, no pipe busy) both run at
// ~30G transactions/s. R6: per-tile LDS counting sort -> all global writes
// coalesced (sorted key tiles + per-tile directory), phase 2 gathers its
// per-partition segments with scattered READS (cheap, pipelined).

constexpr int N_WORDS  = 500000;
constexpr int N_LABELS = 64;
constexpr int SEQ_LEN  = 512;
constexpr int BINS     = (N_LABELS + 1) * (N_LABELS + 1);   // 4225
constexpr int N_CELLS  = N_WORDS * N_LABELS;                // 32,000,000
constexpr int P        = 1000;     // emit partitions; P*CPP == N_CELLS exactly
constexpr int CPP      = 32000;    // cells/partition; u16 counts = 64,000 B LDS
constexpr int TILE_TOK = 4096;     // tokens per phase-1 tile
constexpr int QPT      = TILE_TOK / 4;   // 1024 quads/tile
constexpr int B1 = 1024, G1 = 512;
constexpr int B2 = 1024;
constexpr int FIN_BLOCKS = 5;      // 5*1024 >= 4225

// ---------------- phase 1: tile counting sort + trans hist ----------------

__global__ __launch_bounds__(B1)
void phase1(const int* __restrict__ words, const int* __restrict__ labels,
            unsigned* __restrict__ dir,            // [ntiles][P]  (cnt<<16)|off
            unsigned short* __restrict__ keys,     // [ntiles][TILE_TOK] sorted loc
            unsigned* __restrict__ part_t,         // [G1][BINS] trans partials
            int n, int ntiles) {
    __shared__ unsigned trans[BINS];               // 16.9 KB
    __shared__ unsigned keybuf[TILE_TOK];          // 16 KB  (p<<16)|loc, ~0u = pad
    __shared__ unsigned short sorted[TILE_TOK];    // 8 KB
    __shared__ unsigned cnt[1024];                 // 4 KB (P<=1024)
    __shared__ unsigned scanbuf[1024];             // 4 KB
    __shared__ unsigned cursor[1024];              // 4 KB
    const int tid = threadIdx.x;
    for (int k = tid; k < BINS; k += B1) trans[k] = 0u;

    const int nquads = n >> 2;
    for (int tile = blockIdx.x; tile < ntiles; tile += gridDim.x) {
        const int q0 = tile * QPT;
        const int tq = min(QPT, nquads - q0);
        cnt[tid] = 0u;
        __syncthreads();

        // pass A: one quad per thread; keys -> LDS, partition counts, trans hist
        if (tid < tq) {
            const int q = q0 + tid;
            const int i = q << 2;
            const int4 w4 = reinterpret_cast<const int4*>(words)[q];
            const int4 l4 = reinterpret_cast<const int4*>(labels)[q];
            const int j0 = i & (SEQ_LEN - 1);
            int pre = (j0 == 0) ? N_LABELS : labels[i - 1];
            int wv[4] = {w4.x, w4.y, w4.z, w4.w};
            int lv[4] = {l4.x, l4.y, l4.z, l4.w};
            unsigned pk[4];
            #pragma unroll
            for (int k = 0; k < 4; ++k) {
                const int lab = lv[k];
                unsigned pack = 0xFFFFFFFFu;
                if (wv[k] != 0) {
                    atomicAdd(&trans[lab * (N_LABELS + 1) + pre], 1u);
                    const int w = (wv[k] >= N_WORDS) ? 1 : wv[k];
                    const unsigned key = (unsigned)w * N_LABELS + (unsigned)lab;
                    const unsigned p   = key / CPP;        // magic-mul const div
                    pack = (p << 16) | (key - p * CPP);    // loc < 32000 fits u16
                    atomicAdd(&cnt[p], 1u);
                }
                pk[k] = pack;
                pre = lab;
            }
            reinterpret_cast<uint4*>(keybuf)[tid] = make_uint4(pk[0], pk[1], pk[2], pk[3]);
        }
        __syncthreads();

        // inclusive Hillis-Steele scan of cnt[1024]
        const unsigned myc = cnt[tid];
        unsigned v = myc;
        #pragma unroll
        for (int d = 1; d < 1024; d <<= 1) {
            scanbuf[tid] = v; __syncthreads();
            if (tid >= d) v += scanbuf[tid - d];
            __syncthreads();
        }
        const unsigned off = v - myc;                      // exclusive offset
        cursor[tid] = off;
        if (tid < P) dir[(size_t)tile * P + tid] = (myc << 16) | off;  // coalesced
        __syncthreads();

        // pass B: LDS scatter into sorted order
        const int tt = tq << 2;
        for (int t = tid; t < tt; t += B1) {
            const unsigned pack = keybuf[t];
            if (pack != 0xFFFFFFFFu) {
                const unsigned s = atomicAdd(&cursor[pack >> 16], 1u);
                sorted[s] = (unsigned short)(pack & 0xFFFFu);
            }
        }
        __syncthreads();

        // coalesced write of the sorted tile (8 KB contiguous; garbage tail ok)
        if (tid < TILE_TOK / 8)
            reinterpret_cast<uint4*>(keys + (size_t)tile * TILE_TOK)[tid] =
                reinterpret_cast<const uint4*>(sorted)[tid];
        __syncthreads();
    }

    unsigned* my = part_t + (size_t)blockIdx.x * BINS;
    for (int k = tid; k < BINS; k += B1) my[k] = trans[k];  // plain coalesced
}

// ---------------- directory transpose: dir[t][p] -> dirT[p][t] ----------------

__global__ __launch_bounds__(256)
void transpose_dir(const unsigned* __restrict__ dir, unsigned* __restrict__ dirT,
                   int ntiles, int tstride) {
    __shared__ unsigned tb[32][33];
    const int p0 = blockIdx.x * 32, t0 = blockIdx.y * 32;
    const int tx = threadIdx.x, ty = threadIdx.y;          // block (32,8)
    for (int j = ty; j < 32; j += 8) {
        const int t = t0 + j, p = p0 + tx;
        tb[j][tx] = (t < ntiles && p < P) ? dir[(size_t)t * P + p] : 0u;
    }
    __syncthreads();
    for (int j = ty; j < 32; j += 8) {
        const int p = p0 + j, t = t0 + tx;
        if (p < P && t < tstride) dirT[(size_t)p * tstride + t] = tb[tx][j];
    }
}

// ---------------- phase 2: build emit slices + fused trans finalize ----------------

__global__ __launch_bounds__(B2)
void phase2(const unsigned* __restrict__ dirT,             // [P][tstride]
            const unsigned short* __restrict__ keys,       // [ntiles][TILE_TOK]
            const unsigned* __restrict__ part_t,
            float* __restrict__ out, int ntiles, int tstride) {
    extern __shared__ unsigned h[];                        // 16,000 u32 packed u16
    const unsigned bid = blockIdx.x;

    if (bid >= (unsigned)P) {                              // fused trans finalize
        const int k = (bid - P) * B2 + threadIdx.x;
        if (k < BINS) {
            unsigned s = 0;
            #pragma unroll 8
            for (int pb = 0; pb < G1; ++pb) s += part_t[(size_t)pb * BINS + k];
            out[k] = (float)s;
        }
        return;
    }

    for (int j = threadIdx.x; j < CPP / 2; j += B2) h[j] = 0u;
    __syncthreads();

    const unsigned* drow = dirT + (size_t)bid * tstride;   // coalesced row
    for (int t = threadIdx.x; t < ntiles; t += B2) {
        const unsigned e = drow[t];
        unsigned c = e >> 16;
        const unsigned short* kp = keys + (size_t)t * TILE_TOK + (e & 0xFFFFu);
        for (unsigned i = 0; i < c; ++i) {
            const unsigned loc = kp[i];
            atomicAdd(&h[loc >> 1], (loc & 1u) ? 65536u : 1u);
        }
    }
    __syncthreads();

    // write sweep; emit + p*CPP is ==4 (mod 16) aligned (proven exact in R5)
    float* __restrict__ emit = out + BINS;
    float* dst = emit + (size_t)bid * CPP;
    if (threadIdx.x < 3)
        dst[threadIdx.x] =
            (float)((h[threadIdx.x >> 1] >> ((threadIdx.x & 1u) * 16)) & 0xFFFFu);
    if (threadIdx.x == 3)
        dst[CPP - 1] = (float)(h[(CPP - 1) >> 1] >> 16);
    float4* dst4 = reinterpret_cast<float4*>(dst + 3);
    for (int u = threadIdx.x; u < (CPP - 4) / 4; u += B2) {   // 7999 float4s
        const unsigned w0 = h[2 * u + 1];
        const unsigned w1 = h[2 * u + 2];
        const unsigned w2 = h[2 * u + 3];
        float4 f;
        f.x = (float)(w0 >> 16);
        f.y = (float)(w1 & 0xFFFFu);
        f.z = (float)(w1 >> 16);
        f.w = (float)(w2 & 0xFFFFu);
        dst4[u] = f;
    }
}

// ---------------- fallback (ws too small) ----------------

__global__ __launch_bounds__(256)
void zero_kernel(uint4* __restrict__ out, int out_quads, int out_size) {
    const uint4 z = {0u, 0u, 0u, 0u};
    const int stride = gridDim.x * blockDim.x;
    for (int q = blockIdx.x * blockDim.x + threadIdx.x; q < out_quads; q += stride)
        out[q] = z;
    if (blockIdx.x == 0 && threadIdx.x < (out_size & 3))
        ((unsigned*)out)[(out_quads << 2) + threadIdx.x] = 0u;
}

__global__ __launch_bounds__(1024)
void count_fallback(const int* __restrict__ words, const int* __restrict__ labels,
                    float* __restrict__ out, int nquads) {
    __shared__ unsigned hist[BINS];
    for (int k = threadIdx.x; k < BINS; k += 1024) hist[k] = 0u;
    __syncthreads();
    float* __restrict__ emit = out + BINS;
    const int stride = gridDim.x * blockDim.x;
    for (int q = blockIdx.x * blockDim.x + threadIdx.x; q < nquads; q += stride) {
        const int i = q << 2;
        const int4 w4 = reinterpret_cast<const int4*>(words)[q];
        const int4 l4 = reinterpret_cast<const int4*>(labels)[q];
        const int j0 = i & (SEQ_LEN - 1);
        int pre = (j0 == 0) ? N_LABELS : labels[i - 1];
        int wv[4] = {w4.x, w4.y, w4.z, w4.w};
        int lv[4] = {l4.x, l4.y, l4.z, l4.w};
        #pragma unroll
        for (int k = 0; k < 4; ++k) {
            const int w = wv[k], lab = lv[k];
            if (w != 0) {
                atomicAdd(&hist[lab * (N_LABELS + 1) + pre], 1u);
                const int we = (w >= N_WORDS) ? 1 : w;
                atomicAdd(&emit[(size_t)we * N_LABELS + lab], 1.0f);
            }
            pre = lab;
        }
    }
    __syncthreads();
    for (int k = threadIdx.x; k < BINS; k += 1024) {
        const unsigned c = hist[k];
        if (c) atomicAdd(&out[k], (float)c);
    }
}

// ---------------- launch ----------------

extern "C" void kernel_launch(void* const* d_in, const int* in_sizes, int n_in,
                              void* d_out, int out_size, void* d_ws, size_t ws_size,
                              hipStream_t stream) {
    const int* words  = (const int*)d_in[0];
    const int* labels = (const int*)d_in[1];
    float* out = (float*)d_out;
    const int n = in_sizes[0];

    const int nquads  = n >> 2;
    const int ntiles  = (nquads + QPT - 1) / QPT;
    const int tstride = ((ntiles + 63) / 64) * 64;

    // ws: dir | dirT | keys | part_t
    const size_t dir_bytes  = (size_t)ntiles * P * sizeof(unsigned);
    const size_t dirT_bytes = (size_t)P * tstride * sizeof(unsigned);
    const size_t key_bytes  = (size_t)ntiles * TILE_TOK * sizeof(unsigned short);
    const size_t part_bytes = (size_t)G1 * BINS * sizeof(unsigned);
    const size_t dir_off  = 0;
    const size_t dirT_off = dir_off + ((dir_bytes + 255) & ~size_t(255));
    const size_t key_off  = dirT_off + ((dirT_bytes + 255) & ~size_t(255));
    const size_t part_off = key_off + ((key_bytes + 255) & ~size_t(255));
    const size_t need     = part_off + part_bytes;

    if (ws_size >= need) {
        unsigned*       dir    = (unsigned*)((char*)d_ws + dir_off);
        unsigned*       dirT   = (unsigned*)((char*)d_ws + dirT_off);
        unsigned short* keys   = (unsigned short*)((char*)d_ws + key_off);
        unsigned*       part_t = (unsigned*)((char*)d_ws + part_off);

        phase1<<<G1, B1, 0, stream>>>(words, labels, dir, keys, part_t, n, ntiles);
        dim3 tg((P + 31) / 32, (tstride + 31) / 32);
        transpose_dir<<<tg, dim3(32, 8), 0, stream>>>(dir, dirT, ntiles, tstride);
        phase2<<<P + FIN_BLOCKS, B2, (CPP / 2) * sizeof(unsigned), stream>>>(
            dirT, keys, part_t, out, ntiles, tstride);
    } else {
        const int out_quads = out_size >> 2;
        zero_kernel<<<2048, 256, 0, stream>>>((uint4*)d_out, out_quads, out_size);
        count_fallback<<<512, 1024, 0, stream>>>(words, labels, out, nquads);
    }
}

// Round 7
// 254.492 us; speedup vs baseline: 1.3866x; 1.0472x over previous
//
#include <hip/hip_runtime.h>
#include <hip/hip_bf16.h>

// HMM count-accumulation with NO scattered global writes.
// out = [trans_count 65*65=4225 | emit_count 500000*64=32M] floats.
//
// Measured walls: scattered device-scope atomics (R1: 3.15M -> 165us) and
// scattered u16 stores (R5: 234us fused, no pipe busy) both ~30G txn/s.
// R6 counting-sort removes them. R7: the R6 phase1 LDS scan cost ~40
// block-wide barriers (10 rounds x 2 syncs x 2 tiles); replace with a
// wave-shuffle hierarchical scan (2 barriers), and run the fused trans
// finalize as the FIRST phase2 blocks so it hides under emit blocks.

constexpr int N_WORDS  = 500000;
constexpr int N_LABELS = 64;
constexpr int SEQ_LEN  = 512;
constexpr int BINS     = (N_LABELS + 1) * (N_LABELS + 1);   // 4225
constexpr int N_CELLS  = N_WORDS * N_LABELS;                // 32,000,000
constexpr int P        = 1000;     // emit partitions; P*CPP == N_CELLS exactly
constexpr int CPP      = 32000;    // cells/partition; u16 counts = 64,000 B LDS
constexpr int TILE_TOK = 4096;     // tokens per phase-1 tile
constexpr int QPT      = TILE_TOK / 4;   // 1024 quads/tile
constexpr int B1 = 1024, G1 = 512;
constexpr int B2 = 1024;
constexpr int FIN_BLOCKS = 5;      // 5*1024 >= 4225

// ---------------- phase 1: tile counting sort + trans hist ----------------

__global__ __launch_bounds__(B1)
void phase1(const int* __restrict__ words, const int* __restrict__ labels,
            unsigned* __restrict__ dir,            // [ntiles][P]  (cnt<<16)|off
            unsigned short* __restrict__ keys,     // [ntiles][TILE_TOK] sorted loc
            unsigned* __restrict__ part_t,         // [G1][BINS] trans partials
            int n, int ntiles) {
    __shared__ unsigned trans[BINS];               // 16.9 KB
    __shared__ unsigned keybuf[TILE_TOK];          // 16 KB  (p<<16)|loc, ~0u = pad
    __shared__ unsigned short sorted[TILE_TOK];    // 8 KB
    __shared__ unsigned cnt[1024];                 // 4 KB; reused as scatter cursor
    __shared__ unsigned wsum[16];
    const int tid  = threadIdx.x;
    const int lane = tid & 63;
    for (int k = tid; k < BINS; k += B1) trans[k] = 0u;

    const int nquads = n >> 2;
    for (int tile = blockIdx.x; tile < ntiles; tile += gridDim.x) {
        const int q0 = tile * QPT;
        const int tq = min(QPT, nquads - q0);
        cnt[tid] = 0u;
        __syncthreads();

        // pass A: one quad per thread; keys -> LDS, partition counts, trans hist
        if (tid < tq) {
            const int q = q0 + tid;
            const int i = q << 2;
            const int4 w4 = reinterpret_cast<const int4*>(words)[q];
            const int4 l4 = reinterpret_cast<const int4*>(labels)[q];
            const int j0 = i & (SEQ_LEN - 1);
            int pre = (j0 == 0) ? N_LABELS : labels[i - 1];
            int wv[4] = {w4.x, w4.y, w4.z, w4.w};
            int lv[4] = {l4.x, l4.y, l4.z, l4.w};
            unsigned pk[4];
            #pragma unroll
            for (int k = 0; k < 4; ++k) {
                const int lab = lv[k];
                unsigned pack = 0xFFFFFFFFu;
                if (wv[k] != 0) {
                    atomicAdd(&trans[lab * (N_LABELS + 1) + pre], 1u);
                    const int w = (wv[k] >= N_WORDS) ? 1 : wv[k];
                    const unsigned key = (unsigned)w * N_LABELS + (unsigned)lab;
                    const unsigned p   = key / CPP;        // magic-mul const div
                    pack = (p << 16) | (key - p * CPP);    // loc < 32000 fits u16
                    atomicAdd(&cnt[p], 1u);
                }
                pk[k] = pack;
                pre = lab;
            }
            reinterpret_cast<uint4*>(keybuf)[tid] = make_uint4(pk[0], pk[1], pk[2], pk[3]);
        }
        __syncthreads();

        // hierarchical scan of cnt[1024]: wave shfl scan + wave-sum scan.
        // 2 barriers total (R6's Hillis-Steele: 20 per tile).
        {
            const unsigned c = cnt[tid];
            unsigned v = c;
            #pragma unroll
            for (int d = 1; d < 64; d <<= 1) {
                const unsigned u = __shfl_up(v, d, 64);
                if (lane >= d) v += u;
            }
            if (lane == 63) wsum[tid >> 6] = v;
            __syncthreads();
            if (tid < 16) {
                const unsigned s = wsum[tid];
                unsigned vv = s;
                #pragma unroll
                for (int d = 1; d < 16; d <<= 1) {
                    const unsigned u = __shfl_up(vv, d, 64);
                    if (tid >= d) vv += u;
                }
                wsum[tid] = vv - s;                 // exclusive wave prefix
            }
            __syncthreads();
            const unsigned off = v - c + wsum[tid >> 6];  // exclusive offset
            cnt[tid] = off;                                // reuse as cursor
            if (tid < P) dir[(size_t)tile * P + tid] = (c << 16) | off;  // coalesced
        }
        __syncthreads();

        // pass B: LDS scatter into sorted order
        const int tt = tq << 2;
        for (int t = tid; t < tt; t += B1) {
            const unsigned pack = keybuf[t];
            if (pack != 0xFFFFFFFFu) {
                const unsigned s = atomicAdd(&cnt[pack >> 16], 1u);
                sorted[s] = (unsigned short)(pack & 0xFFFFu);
            }
        }
        __syncthreads();

        // coalesced write of the sorted tile (8 KB contiguous; garbage tail ok)
        if (tid < TILE_TOK / 8)
            reinterpret_cast<uint4*>(keys + (size_t)tile * TILE_TOK)[tid] =
                reinterpret_cast<const uint4*>(sorted)[tid];
        __syncthreads();
    }

    unsigned* my = part_t + (size_t)blockIdx.x * BINS;
    for (int k = tid; k < BINS; k += B1) my[k] = trans[k];  // plain coalesced
}

// ---------------- directory transpose: dir[t][p] -> dirT[p][t] ----------------

__global__ __launch_bounds__(256)
void transpose_dir(const unsigned* __restrict__ dir, unsigned* __restrict__ dirT,
                   int ntiles, int tstride) {
    __shared__ unsigned tb[32][33];
    const int p0 = blockIdx.x * 32, t0 = blockIdx.y * 32;
    const int tx = threadIdx.x, ty = threadIdx.y;          // block (32,8)
    for (int j = ty; j < 32; j += 8) {
        const int t = t0 + j, p = p0 + tx;
        tb[j][tx] = (t < ntiles && p < P) ? dir[(size_t)t * P + p] : 0u;
    }
    __syncthreads();
    for (int j = ty; j < 32; j += 8) {
        const int p = p0 + j, t = t0 + tx;
        if (p < P && t < tstride) dirT[(size_t)p * tstride + t] = tb[tx][j];
    }
}

// ---------------- phase 2: emit slices + fused trans finalize ----------------

__global__ __launch_bounds__(B2)
void phase2(const unsigned* __restrict__ dirT,             // [P][tstride]
            const unsigned short* __restrict__ keys,       // [ntiles][TILE_TOK]
            const unsigned* __restrict__ part_t,
            float* __restrict__ out, int ntiles, int tstride) {
    extern __shared__ unsigned h[];                        // 16,000 u32 packed u16
    const unsigned bid = blockIdx.x;

    if (bid < (unsigned)FIN_BLOCKS) {                      // fused trans finalize
        const int k = bid * B2 + threadIdx.x;              // runs in round 1,
        if (k < BINS) {                                    // hidden under emit blocks
            unsigned s = 0;
            #pragma unroll 8
            for (int pb = 0; pb < G1; ++pb) s += part_t[(size_t)pb * BINS + k];
            out[k] = (float)s;
        }
        return;
    }
    const unsigned p = bid - FIN_BLOCKS;                   // partition index

    for (int j = threadIdx.x; j < CPP / 2; j += B2) h[j] = 0u;
    __syncthreads();

    const unsigned* drow = dirT + (size_t)p * tstride;     // coalesced row
    for (int t = threadIdx.x; t < ntiles; t += B2) {
        const unsigned e = drow[t];
        unsigned c = e >> 16;
        const unsigned short* kp = keys + (size_t)t * TILE_TOK + (e & 0xFFFFu);
        for (unsigned i = 0; i < c; ++i) {
            const unsigned loc = kp[i];
            atomicAdd(&h[loc >> 1], (loc & 1u) ? 65536u : 1u);
        }
    }
    __syncthreads();

    // write sweep; emit + p*CPP is ==4 (mod 16) aligned (proven exact R5/R6)
    float* __restrict__ emit = out + BINS;
    float* dst = emit + (size_t)p * CPP;
    if (threadIdx.x < 3)
        dst[threadIdx.x] =
            (float)((h[threadIdx.x >> 1] >> ((threadIdx.x & 1u) * 16)) & 0xFFFFu);
    if (threadIdx.x == 3)
        dst[CPP - 1] = (float)(h[(CPP - 1) >> 1] >> 16);
    float4* dst4 = reinterpret_cast<float4*>(dst + 3);
    for (int u = threadIdx.x; u < (CPP - 4) / 4; u += B2) {   // 7999 float4s
        const unsigned w0 = h[2 * u + 1];
        const unsigned w1 = h[2 * u + 2];
        const unsigned w2 = h[2 * u + 3];
        float4 f;
        f.x = (float)(w0 >> 16);
        f.y = (float)(w1 & 0xFFFFu);
        f.z = (float)(w1 >> 16);
        f.w = (float)(w2 & 0xFFFFu);
        dst4[u] = f;
    }
}

// ---------------- fallback (ws too small) ----------------

__global__ __launch_bounds__(256)
void zero_kernel(uint4* __restrict__ out, int out_quads, int out_size) {
    const uint4 z = {0u, 0u, 0u, 0u};
    const int stride = gridDim.x * blockDim.x;
    for (int q = blockIdx.x * blockDim.x + threadIdx.x; q < out_quads; q += stride)
        out[q] = z;
    if (blockIdx.x == 0 && threadIdx.x < (out_size & 3))
        ((unsigned*)out)[(out_quads << 2) + threadIdx.x] = 0u;
}

__global__ __launch_bounds__(1024)
void count_fallback(const int* __restrict__ words, const int* __restrict__ labels,
                    float* __restrict__ out, int nquads) {
    __shared__ unsigned hist[BINS];
    for (int k = threadIdx.x; k < BINS; k += 1024) hist[k] = 0u;
    __syncthreads();
    float* __restrict__ emit = out + BINS;
    const int stride = gridDim.x * blockDim.x;
    for (int q = blockIdx.x * blockDim.x + threadIdx.x; q < nquads; q += stride) {
        const int i = q << 2;
        const int4 w4 = reinterpret_cast<const int4*>(words)[q];
        const int4 l4 = reinterpret_cast<const int4*>(labels)[q];
        const int j0 = i & (SEQ_LEN - 1);
        int pre = (j0 == 0) ? N_LABELS : labels[i - 1];
        int wv[4] = {w4.x, w4.y, w4.z, w4.w};
        int lv[4] = {l4.x, l4.y, l4.z, l4.w};
        #pragma unroll
        for (int k = 0; k < 4; ++k) {
            const int w = wv[k], lab = lv[k];
            if (w != 0) {
                atomicAdd(&hist[lab * (N_LABELS + 1) + pre], 1u);
                const int we = (w >= N_WORDS) ? 1 : w;
                atomicAdd(&emit[(size_t)we * N_LABELS + lab], 1.0f);
            }
            pre = lab;
        }
    }
    __syncthreads();
    for (int k = threadIdx.x; k < BINS; k += 1024) {
        const unsigned c = hist[k];
        if (c) atomicAdd(&out[k], (float)c);
    }
}

// ---------------- launch ----------------

extern "C" void kernel_launch(void* const* d_in, const int* in_sizes, int n_in,
                              void* d_out, int out_size, void* d_ws, size_t ws_size,
                              hipStream_t stream) {
    const int* words  = (const int*)d_in[0];
    const int* labels = (const int*)d_in[1];
    float* out = (float*)d_out;
    const int n = in_sizes[0];

    const int nquads  = n >> 2;
    const int ntiles  = (nquads + QPT - 1) / QPT;
    const int tstride = ((ntiles + 63) / 64) * 64;

    // ws: dir | dirT | keys | part_t
    const size_t dir_bytes  = (size_t)ntiles * P * sizeof(unsigned);
    const size_t dirT_bytes = (size_t)P * tstride * sizeof(unsigned);
    const size_t key_bytes  = (size_t)ntiles * TILE_TOK * sizeof(unsigned short);
    const size_t part_bytes = (size_t)G1 * BINS * sizeof(unsigned);
    const size_t dir_off  = 0;
    const size_t dirT_off = dir_off + ((dir_bytes + 255) & ~size_t(255));
    const size_t key_off  = dirT_off + ((dirT_bytes + 255) & ~size_t(255));
    const size_t part_off = key_off + ((key_bytes + 255) & ~size_t(255));
    const size_t need     = part_off + part_bytes;

    if (ws_size >= need) {
        unsigned*       dir    = (unsigned*)((char*)d_ws + dir_off);
        unsigned*       dirT   = (unsigned*)((char*)d_ws + dirT_off);
        unsigned short* keys   = (unsigned short*)((char*)d_ws + key_off);
        unsigned*       part_t = (unsigned*)((char*)d_ws + part_off);

        phase1<<<G1, B1, 0, stream>>>(words, labels, dir, keys, part_t, n, ntiles);
        dim3 tg((P + 31) / 32, (tstride + 31) / 32);
        transpose_dir<<<tg, dim3(32, 8), 0, stream>>>(dir, dirT, ntiles, tstride);
        phase2<<<P + FIN_BLOCKS, B2, (CPP / 2) * sizeof(unsigned), stream>>>(
            dirT, keys, part_t, out, ntiles, tstride);
    } else {
        const int out_quads = out_size >> 2;
        zero_kernel<<<2048, 256, 0, stream>>>((uint4*)d_out, out_quads, out_size);
        count_fallback<<<512, 1024, 0, stream>>>(words, labels, out, nquads);
    }
}